// Round 22
// baseline (178.566 us; speedup 1.0000x reference)
//
#include <hip/hip_runtime.h>
#include <hip/hip_bf16.h>
#include <cstdint>

#define S_LEN 4096
#define NHEAD 4
#define HDIM 32
#define HID 128
#define CBATCH 4
#define EPSW 1e-8f
#define NCHUNKS (S_LEN / 32)

typedef __attribute__((ext_vector_type(8))) short short8v;
typedef __attribute__((ext_vector_type(4))) float float4v;

__device__ __forceinline__ unsigned short f2bf(float f) {
    unsigned int u = __float_as_uint(f);
    return (unsigned short)((u + 0x7fffu + ((u >> 16) & 1u)) >> 16);
}

__device__ __forceinline__ float exp2_asm(float x) {
    float r;
    asm("v_exp_f32 %0, %1" : "=v"(r) : "v"(x));
    return r;
}

__device__ __forceinline__ unsigned cvt_pk_bf16(float lo, float hi) {
    unsigned r;
    asm("v_cvt_pk_bf16_f32 %0, %1, %2" : "=v"(r) : "v"(lo), "v"(hi));
    return r;
}

// async global->LDS, 16B per lane; LDS dest = wave-uniform base + lane*16
__device__ __forceinline__ void gload16(const void* g, void* l) {
    __builtin_amdgcn_global_load_lds(
        (const __attribute__((address_space(1))) void*)g,
        (__attribute__((address_space(3))) void*)l,
        16, 0, 0);
}

// ---------------------------------------------------------------------------
// Kernel 1: fused QKV projection.  out = (x @ W.T + b) [* SCALE*log2e for Q]
// ---------------------------------------------------------------------------
__global__ __launch_bounds__(256) void qkv_proj_kernel(
    const float* __restrict__ x,
    const float* __restrict__ Wq, const float* __restrict__ bq,
    const float* __restrict__ Wk, const float* __restrict__ bk,
    const float* __restrict__ Wv, const float* __restrict__ bv,
    unsigned short* __restrict__ Qo, unsigned short* __restrict__ Ko,
    unsigned short* __restrict__ Vo)
{
    __shared__ float xs[64][132];
    __shared__ float wsT[64][68];

    const int tid = threadIdx.x;
    const int mrow0 = blockIdx.x * 64;
    const int n0 = blockIdx.y * 64;
    const int p = blockIdx.z;
    const float* W    = (p == 0) ? Wq : (p == 1) ? Wk : Wv;
    const float* bias = (p == 0) ? bq : (p == 1) ? bk : bv;
    unsigned short* Out = (p == 0) ? Qo : (p == 1) ? Ko : Vo;

    for (int i = tid; i < 64 * 32; i += 256) {
        int r = i >> 5, c4 = (i & 31) * 4;
        *(float4*)&xs[r][c4] = *(const float4*)&x[(size_t)(mrow0 + r) * HID + c4];
    }

    float acc[4][4] = {};
    const int tr = tid >> 4;
    const int tc = tid & 15;

    for (int ph = 0; ph < 2; ++ph) {
        __syncthreads();
        for (int i = tid; i < 64 * 16; i += 256) {
            int r = i >> 4, c4 = (i & 15) * 4;
            float4 wv = *(const float4*)&W[(size_t)(n0 + r) * HID + ph * 64 + c4];
            wsT[c4 + 0][r] = wv.x;
            wsT[c4 + 1][r] = wv.y;
            wsT[c4 + 2][r] = wv.z;
            wsT[c4 + 3][r] = wv.w;
        }
        __syncthreads();
        #pragma unroll 4
        for (int k4 = 0; k4 < 16; ++k4) {
            float4 xv[4];
            #pragma unroll
            for (int i = 0; i < 4; ++i)
                xv[i] = *(const float4*)&xs[tr * 4 + i][ph * 64 + k4 * 4];
            #pragma unroll
            for (int kk = 0; kk < 4; ++kk) {
                float4 wv = *(const float4*)&wsT[k4 * 4 + kk][tc * 4];
                #pragma unroll
                for (int i = 0; i < 4; ++i) {
                    float xk = ((const float*)&xv[i])[kk];
                    acc[i][0] += xk * wv.x;
                    acc[i][1] += xk * wv.y;
                    acc[i][2] += xk * wv.z;
                    acc[i][3] += xk * wv.w;
                }
            }
        }
    }

    // SCALE * log2(e): exp(s*SCALE) == exp2(s * SCALE * log2e)
    const float scale = (p == 0) ? 0.25500544458521289f : 1.0f;
    float4 bv4 = *(const float4*)&bias[n0 + tc * 4];
    const int nbase = n0 + tc * 4;
    const int h = nbase >> 5;
    const int d = nbase & 31;
    #pragma unroll
    for (int i = 0; i < 4; ++i) {
        int m = mrow0 + tr * 4 + i;
        int c = m >> 12, s = m & 4095;
        unsigned short pk[4];
        pk[0] = f2bf((acc[i][0] + bv4.x) * scale);
        pk[1] = f2bf((acc[i][1] + bv4.y) * scale);
        pk[2] = f2bf((acc[i][2] + bv4.z) * scale);
        pk[3] = f2bf((acc[i][3] + bv4.w) * scale);
        *(uint2*)&Out[((size_t)(c * NHEAD + h) * S_LEN + s) * HDIM + d] = *(uint2*)pk;
    }
}

// ---------------------------------------------------------------------------
// Kernel 2: repack V (C,NH,S,HD) -> Vt2: exact PV A-fragment order.
// ---------------------------------------------------------------------------
__global__ __launch_bounds__(256) void vtrans_kernel(
    const unsigned short* __restrict__ V, unsigned short* __restrict__ Vt2)
{
    __shared__ unsigned short vs[64][40];
    const int tid = threadIdx.x;
    const int chh = blockIdx.y;
    const int s0 = blockIdx.x * 64;
    const size_t base = (size_t)chh * S_LEN * HDIM;
    {
        int r = tid >> 2, ch = (tid & 3) * 8;
        *(uint4*)&vs[r][ch] = *(const uint4*)&V[base + (size_t)(s0 + r) * HDIM + ch];
    }
    __syncthreads();
    {
        const int lchunk = tid >> 7;         // 0..1
        const int db = (tid >> 6) & 1;       // 0..1
        const int l = tid & 63;
        const int li = l & 15;
        const int g = l >> 4;
        unsigned short pk[8];
        #pragma unroll
        for (int j = 0; j < 8; ++j) {
            int key = lchunk * 32 + ((j < 4) ? (4 * g + j) : (16 + 4 * g + (j - 4)));
            pk[j] = vs[key][db * 16 + li];
        }
        size_t chunk = (size_t)(s0 >> 5) + lchunk;
        *(uint4*)&Vt2[(((size_t)chh * 2 + db) * NCHUNKS + chunk) * 512 + l * 8] = *(uint4*)pk;
    }
}

// ---------------------------------------------------------------------------
// Kernel 3: attention, split-K, dual key-tranche A/B (64 keys/iter) —
// r21 body VERBATIM (passing).  Only the NS instantiation changes (8):
// 4096 blocks of half the work fixes the batch-quantization waste
// (2048 blocks / 1536 resident = 2 serial batches, 2nd mostly idle).
// ew triple-buffered LDS (buf = it%3); kv fresh per iter into regs.
// vmcnt (FIFO per iter: kv x8 then ew x2): steady 10, last iter 8.
// Denominator via ones-MFMA; s_setprio around compute cluster.
// NOTE: plain __launch_bounds__(256) — (256,4) was the r3/5/6/7 poison.
// ---------------------------------------------------------------------------
template<int NS>
__global__ __launch_bounds__(256) void attn_kernel(
    const unsigned short* __restrict__ Q, const unsigned short* __restrict__ K,
    const unsigned short* __restrict__ Vt2, const float* __restrict__ ew,
    unsigned short* __restrict__ partO, float* __restrict__ den)
{
    const int KCHUNK = S_LEN / NS;
    const int NIT = KCHUNK / 64;

    __shared__ float ew_lds[3][2048];            // 3 x 8KB: [A 4 regions | B 4 regions]

    const int tid = threadIdx.x;
    const int w = tid >> 6;          // head
    const int lane = tid & 63;
    const int li = lane & 15;
    const int g = lane >> 4;
    const int c = blockIdx.y;
    const int qbase = blockIdx.x * 32;
    const int split = blockIdx.z;
    const int kb0 = split * KCHUNK;
    const int chh = c * NHEAD + w;

    const size_t hb = (size_t)chh * S_LEN * HDIM;
    const unsigned short* Qh = Q + hb;
    const unsigned short* Kh = K + hb;
    const float* ewc = ew + (size_t)c * S_LEN * S_LEN;

    short8v qf0 = *(const short8v*)&Qh[(size_t)(qbase + li) * HDIM + g * 8];
    short8v qf1 = *(const short8v*)&Qh[(size_t)(qbase + 16 + li) * HDIM + g * 8];

    short8v ones;
    #pragma unroll
    for (int j = 0; j < 8; ++j) ones[j] = (short)0x3F80;  // bf16 1.0

    // ew region w: rows qbase + (w>>1)*16 + li, cols kb + (w&1)*16 + g*4
    const float* ewA_src = ewc + (size_t)(qbase + (w >> 1) * 16 + li) * S_LEN + kb0
                         + (w & 1) * 16 + g * 4;
    const float* ewB_src = ewA_src + 32;
    const unsigned short* kp  = Kh + (size_t)(kb0 + li) * HDIM + g * 8;
    const unsigned short* vp0 = Vt2 + (((size_t)chh * 2 + 0) * NCHUNKS + (kb0 >> 5)) * 512 + lane * 8;
    const unsigned short* vp1 = Vt2 + (((size_t)chh * 2 + 1) * NCHUNKS + (kb0 >> 5)) * 512 + lane * 8;

    float4v o00 = {}, o01 = {}, o10 = {}, o11 = {};
    float4v dacc0 = {}, dacc1 = {};
    const float4v zero4 = {0.f, 0.f, 0.f, 0.f};

    #define CFENCE() asm volatile("" ::: "memory")

    // prologue: stage ew(0) A,B into buf 0
    gload16(ewA_src, &ew_lds[0][w * 256]);
    gload16(ewB_src, &ew_lds[0][1024 + w * 256]);
    ewA_src += 64; ewB_src += 64;
    CFENCE();

    int bew = 0;   // compute buffer = it % 3
    int sew = 1;   // stage buffer   = (it+1) % 3
    for (int it = 0; it < NIT; ++it) {
        // kv(it) A+B into regs (L2-resident; compiler auto-waits before use)
        short8v kfA0 = *(const short8v*)kp;
        short8v kfA1 = *(const short8v*)(kp + 512);
        short8v vfA0 = *(const short8v*)vp0;
        short8v vfA1 = *(const short8v*)vp1;
        short8v kfB0 = *(const short8v*)(kp + 1024);
        short8v kfB1 = *(const short8v*)(kp + 1536);
        short8v vfB0 = *(const short8v*)(vp0 + 512);
        short8v vfB1 = *(const short8v*)(vp1 + 512);
        CFENCE();
        if (it + 1 < NIT) {
            gload16(ewA_src, &ew_lds[sew][w * 256]);
            gload16(ewB_src, &ew_lds[sew][1024 + w * 256]);
            ewA_src += 64; ewB_src += 64;
        }
        // wait for own ew(it): younger = kv x8 [+ ew(it+1) x2 if staged]
        if (it + 1 < NIT) asm volatile("s_waitcnt vmcnt(10)" ::: "memory");
        else              asm volatile("s_waitcnt vmcnt(8)" ::: "memory");
        __builtin_amdgcn_s_barrier();
        CFENCE();

        const float* eb = ew_lds[bew];

        __builtin_amdgcn_s_setprio(1);
        // ---- tranche A ----
        {
            float4 e00 = *(const float4*)&eb[lane * 4];
            float4 e01 = *(const float4*)&eb[256 + lane * 4];
            float4 e10 = *(const float4*)&eb[512 + lane * 4];
            float4 e11 = *(const float4*)&eb[768 + lane * 4];

            float4v s0 = __builtin_amdgcn_mfma_f32_16x16x32_bf16(kfA0, qf0, zero4, 0, 0, 0);
            float4v s1 = __builtin_amdgcn_mfma_f32_16x16x32_bf16(kfA1, qf0, zero4, 0, 0, 0);
            float4v s2 = __builtin_amdgcn_mfma_f32_16x16x32_bf16(kfA0, qf1, zero4, 0, 0, 0);
            float4v s3 = __builtin_amdgcn_mfma_f32_16x16x32_bf16(kfA1, qf1, zero4, 0, 0, 0);

            float p0 = fmaxf(e00.x, EPSW) * exp2_asm(s0[0]);
            float p1 = fmaxf(e00.y, EPSW) * exp2_asm(s0[1]);
            float p2 = fmaxf(e00.z, EPSW) * exp2_asm(s0[2]);
            float p3 = fmaxf(e00.w, EPSW) * exp2_asm(s0[3]);
            float p4 = fmaxf(e01.x, EPSW) * exp2_asm(s1[0]);
            float p5 = fmaxf(e01.y, EPSW) * exp2_asm(s1[1]);
            float p6 = fmaxf(e01.z, EPSW) * exp2_asm(s1[2]);
            float p7 = fmaxf(e01.w, EPSW) * exp2_asm(s1[3]);
            union { short8v v; unsigned u[4]; } pu0;
            pu0.u[0] = cvt_pk_bf16(p0, p1);
            pu0.u[1] = cvt_pk_bf16(p2, p3);
            pu0.u[2] = cvt_pk_bf16(p4, p5);
            pu0.u[3] = cvt_pk_bf16(p6, p7);
            o00 = __builtin_amdgcn_mfma_f32_16x16x32_bf16(vfA0, pu0.v, o00, 0, 0, 0);
            o01 = __builtin_amdgcn_mfma_f32_16x16x32_bf16(vfA1, pu0.v, o01, 0, 0, 0);
            dacc0 = __builtin_amdgcn_mfma_f32_16x16x32_bf16(ones, pu0.v, dacc0, 0, 0, 0);

            float r0 = fmaxf(e10.x, EPSW) * exp2_asm(s2[0]);
            float r1 = fmaxf(e10.y, EPSW) * exp2_asm(s2[1]);
            float r2 = fmaxf(e10.z, EPSW) * exp2_asm(s2[2]);
            float r3 = fmaxf(e10.w, EPSW) * exp2_asm(s2[3]);
            float r4 = fmaxf(e11.x, EPSW) * exp2_asm(s3[0]);
            float r5 = fmaxf(e11.y, EPSW) * exp2_asm(s3[1]);
            float r6 = fmaxf(e11.z, EPSW) * exp2_asm(s3[2]);
            float r7 = fmaxf(e11.w, EPSW) * exp2_asm(s3[3]);
            union { short8v v; unsigned u[4]; } pu1;
            pu1.u[0] = cvt_pk_bf16(r0, r1);
            pu1.u[1] = cvt_pk_bf16(r2, r3);
            pu1.u[2] = cvt_pk_bf16(r4, r5);
            pu1.u[3] = cvt_pk_bf16(r6, r7);
            o10 = __builtin_amdgcn_mfma_f32_16x16x32_bf16(vfA0, pu1.v, o10, 0, 0, 0);
            o11 = __builtin_amdgcn_mfma_f32_16x16x32_bf16(vfA1, pu1.v, o11, 0, 0, 0);
            dacc1 = __builtin_amdgcn_mfma_f32_16x16x32_bf16(ones, pu1.v, dacc1, 0, 0, 0);
        }

        // ---- tranche B (independent of A until oacc joins) ----
        {
            float4 e00 = *(const float4*)&eb[1024 + lane * 4];
            float4 e01 = *(const float4*)&eb[1280 + lane * 4];
            float4 e10 = *(const float4*)&eb[1536 + lane * 4];
            float4 e11 = *(const float4*)&eb[1792 + lane * 4];

            float4v s0 = __builtin_amdgcn_mfma_f32_16x16x32_bf16(kfB0, qf0, zero4, 0, 0, 0);
            float4v s1 = __builtin_amdgcn_mfma_f32_16x16x32_bf16(kfB1, qf0, zero4, 0, 0, 0);
            float4v s2 = __builtin_amdgcn_mfma_f32_16x16x32_bf16(kfB0, qf1, zero4, 0, 0, 0);
            float4v s3 = __builtin_amdgcn_mfma_f32_16x16x32_bf16(kfB1, qf1, zero4, 0, 0, 0);

            float p0 = fmaxf(e00.x, EPSW) * exp2_asm(s0[0]);
            float p1 = fmaxf(e00.y, EPSW) * exp2_asm(s0[1]);
            float p2 = fmaxf(e00.z, EPSW) * exp2_asm(s0[2]);
            float p3 = fmaxf(e00.w, EPSW) * exp2_asm(s0[3]);
            float p4 = fmaxf(e01.x, EPSW) * exp2_asm(s1[0]);
            float p5 = fmaxf(e01.y, EPSW) * exp2_asm(s1[1]);
            float p6 = fmaxf(e01.z, EPSW) * exp2_asm(s1[2]);
            float p7 = fmaxf(e01.w, EPSW) * exp2_asm(s1[3]);
            union { short8v v; unsigned u[4]; } pu0;
            pu0.u[0] = cvt_pk_bf16(p0, p1);
            pu0.u[1] = cvt_pk_bf16(p2, p3);
            pu0.u[2] = cvt_pk_bf16(p4, p5);
            pu0.u[3] = cvt_pk_bf16(p6, p7);
            o00 = __builtin_amdgcn_mfma_f32_16x16x32_bf16(vfB0, pu0.v, o00, 0, 0, 0);
            o01 = __builtin_amdgcn_mfma_f32_16x16x32_bf16(vfB1, pu0.v, o01, 0, 0, 0);
            dacc0 = __builtin_amdgcn_mfma_f32_16x16x32_bf16(ones, pu0.v, dacc0, 0, 0, 0);

            float r0 = fmaxf(e10.x, EPSW) * exp2_asm(s2[0]);
            float r1 = fmaxf(e10.y, EPSW) * exp2_asm(s2[1]);
            float r2 = fmaxf(e10.z, EPSW) * exp2_asm(s2[2]);
            float r3 = fmaxf(e10.w, EPSW) * exp2_asm(s2[3]);
            float r4 = fmaxf(e11.x, EPSW) * exp2_asm(s3[0]);
            float r5 = fmaxf(e11.y, EPSW) * exp2_asm(s3[1]);
            float r6 = fmaxf(e11.z, EPSW) * exp2_asm(s3[2]);
            float r7 = fmaxf(e11.w, EPSW) * exp2_asm(s3[3]);
            union { short8v v; unsigned u[4]; } pu1;
            pu1.u[0] = cvt_pk_bf16(r0, r1);
            pu1.u[1] = cvt_pk_bf16(r2, r3);
            pu1.u[2] = cvt_pk_bf16(r4, r5);
            pu1.u[3] = cvt_pk_bf16(r6, r7);
            o10 = __builtin_amdgcn_mfma_f32_16x16x32_bf16(vfB0, pu1.v, o10, 0, 0, 0);
            o11 = __builtin_amdgcn_mfma_f32_16x16x32_bf16(vfB1, pu1.v, o11, 0, 0, 0);
            dacc1 = __builtin_amdgcn_mfma_f32_16x16x32_bf16(ones, pu1.v, dacc1, 0, 0, 0);
        }
        __builtin_amdgcn_s_setprio(0);

        kp += 2048;          // 64 keys * 32 dims
        vp0 += 1024;         // 2 chunks
        vp1 += 1024;
        bew = (bew == 2) ? 0 : bew + 1;
        sew = (sew == 2) ? 0 : sew + 1;
    }
    #undef CFENCE

    // every C-row of dacc holds the full key-sum for q-col (lane&15)
    const float den0 = dacc0[0];
    const float den1 = dacc1[0];

    const size_t pbase = (((size_t)split * CBATCH + c) * NHEAD + w) * S_LEN + qbase;
    {
        const size_t pb = pbase + li;
        uint2 s;
        s.x = cvt_pk_bf16(o00[0], o00[1]);
        s.y = cvt_pk_bf16(o00[2], o00[3]);
        *(uint2*)&partO[pb * HDIM + 0 * 16 + g * 4] = s;
        s.x = cvt_pk_bf16(o01[0], o01[1]);
        s.y = cvt_pk_bf16(o01[2], o01[3]);
        *(uint2*)&partO[pb * HDIM + 1 * 16 + g * 4] = s;
        if (g == 0) den[pb] = den0;
    }
    {
        const size_t pb = pbase + 16 + li;
        uint2 s;
        s.x = cvt_pk_bf16(o10[0], o10[1]);
        s.y = cvt_pk_bf16(o10[2], o10[3]);
        *(uint2*)&partO[pb * HDIM + 0 * 16 + g * 4] = s;
        s.x = cvt_pk_bf16(o11[0], o11[1]);
        s.y = cvt_pk_bf16(o11[2], o11[3]);
        *(uint2*)&partO[pb * HDIM + 1 * 16 + g * 4] = s;
        if (g == 0) den[pb] = den1;
    }
}

// ---------------------------------------------------------------------------
// Kernel 4: combine NS splits (bf16 partO) -> normalized attn out, fp32.
// ---------------------------------------------------------------------------
template<int NS>
__global__ __launch_bounds__(256) void combine_kernel(
    const unsigned short* __restrict__ pO, const float* __restrict__ den,
    float* __restrict__ attnbuf)
{
    const int idx = blockIdx.x * 256 + threadIdx.x;
    const int d4 = idx & 7;
    const int q  = (idx >> 3) & (S_LEN - 1);
    const int h  = (idx >> 15) & 3;
    const int c  = idx >> 17;

    const size_t bq = ((size_t)c * NHEAD + h) * S_LEN + q;
    const size_t plane = (size_t)CBATCH * NHEAD * S_LEN;
    float4 acc = {0.f, 0.f, 0.f, 0.f};
    float dsum = 0.f;
    #pragma unroll
    for (int s = 0; s < NS; ++s) {
        const size_t b = (size_t)s * plane + bq;
        uint2 a = *(const uint2*)&pO[b * HDIM + d4 * 4];
        acc.x += __uint_as_float(a.x << 16);
        acc.y += __uint_as_float(a.x & 0xffff0000u);
        acc.z += __uint_as_float(a.y << 16);
        acc.w += __uint_as_float(a.y & 0xffff0000u);
        dsum += den[b];
    }
    float inv = 1.0f / dsum;
    float4 o;
    o.x = acc.x * inv;
    o.y = acc.y * inv;
    o.z = acc.z * inv;
    o.w = acc.w * inv;
    *(float4*)&attnbuf[((size_t)c * S_LEN + q) * HID + h * HDIM + d4 * 4] = o;
}

// ---------------------------------------------------------------------------
// Kernel 5: output projection. out = attnbuf @ Wo.T + bo   (all fp32)
// ---------------------------------------------------------------------------
__global__ __launch_bounds__(256) void out_proj_kernel(
    const float* __restrict__ ain, const float* __restrict__ Wo,
    const float* __restrict__ bo, float* __restrict__ out)
{
    __shared__ float xs[64][132];
    __shared__ float wsT[64][68];

    const int tid = threadIdx.x;
    const int mrow0 = blockIdx.x * 64;
    const int n0 = blockIdx.y * 64;

    for (int i = tid; i < 64 * 32; i += 256) {
        int r = i >> 5, c4 = (i & 31) * 4;
        *(float4*)&xs[r][c4] = *(const float4*)&ain[(size_t)(mrow0 + r) * HID + c4];
    }

    float acc[4][4] = {};
    const int tr = tid >> 4;
    const int tc = tid & 15;

    for (int ph = 0; ph < 2; ++ph) {
        __syncthreads();
        for (int i = tid; i < 64 * 16; i += 256) {
            int r = i >> 4, c4 = (i & 15) * 4;
            float4 wv = *(const float4*)&Wo[(size_t)(n0 + r) * HID + ph * 64 + c4];
            wsT[c4 + 0][r] = wv.x;
            wsT[c4 + 1][r] = wv.y;
            wsT[c4 + 2][r] = wv.z;
            wsT[c4 + 3][r] = wv.w;
        }
        __syncthreads();
        #pragma unroll 4
        for (int k4 = 0; k4 < 16; ++k4) {
            float4 xv[4];
            #pragma unroll
            for (int i = 0; i < 4; ++i)
                xv[i] = *(const float4*)&xs[tr * 4 + i][ph * 64 + k4 * 4];
            #pragma unroll
            for (int kk = 0; kk < 4; ++kk) {
                float4 wv = *(const float4*)&wsT[k4 * 4 + kk][tc * 4];
                #pragma unroll
                for (int i = 0; i < 4; ++i) {
                    float xk = ((const float*)&xv[i])[kk];
                    acc[i][0] += xk * wv.x;
                    acc[i][1] += xk * wv.y;
                    acc[i][2] += xk * wv.z;
                    acc[i][3] += xk * wv.w;
                }
            }
        }
    }

    float4 bv4 = *(const float4*)&bo[n0 + tc * 4];
    #pragma unroll
    for (int i = 0; i < 4; ++i) {
        int m = mrow0 + tr * 4 + i;
        float4 o;
        o.x = acc[i][0] + bv4.x;
        o.y = acc[i][1] + bv4.y;
        o.z = acc[i][2] + bv4.z;
        o.w = acc[i][3] + bv4.w;
        *(float4*)&out[(size_t)m * HID + n0 + tc * 4] = o;
    }
}

extern "C" void kernel_launch(void* const* d_in, const int* in_sizes, int n_in,
                              void* d_out, int out_size, void* d_ws, size_t ws_size,
                              hipStream_t stream) {
    const float* x  = (const float*)d_in[0];
    const float* ew = (const float*)d_in[1];
    const float* Wq = (const float*)d_in[2];
    const float* bq = (const float*)d_in[3];
    const float* Wk = (const float*)d_in[4];
    const float* bk = (const float*)d_in[5];
    const float* Wv = (const float*)d_in[6];
    const float* bv = (const float*)d_in[7];
    const float* Wo = (const float*)d_in[8];
    const float* bo = (const float*)d_in[9];
    float* out = (float*)d_out;

    char* ws = (char*)d_ws;
    const size_t QSZ = (size_t)CBATCH * NHEAD * S_LEN * HDIM * sizeof(unsigned short);  // 4 MiB
    const size_t PLANE_O16 = (size_t)CBATCH * NHEAD * S_LEN * HDIM * sizeof(unsigned short); // 4 MiB
    const size_t PLANE_D = (size_t)CBATCH * NHEAD * S_LEN * sizeof(float);              // 256 KiB

    const size_t need8 = 3 * QSZ + 8 * PLANE_O16 + 8 * PLANE_D;   // ~46 MB
    const size_t need4 = 3 * QSZ + 4 * PLANE_O16 + 4 * PLANE_D;
    const int ns = (ws_size >= need8) ? 8 : (ws_size >= need4) ? 4 : 2;

    unsigned short* Qw  = (unsigned short*)(ws);
    unsigned short* Kw  = (unsigned short*)(ws + QSZ);
    unsigned short* Vt2 = (unsigned short*)(ws + 2 * QSZ);
    unsigned short* Vw  = (unsigned short*)(ws + 3 * QSZ);
    unsigned short* partO = (unsigned short*)(ws + 3 * QSZ);   // overlaps dead Vw
    float* den   = (float*)(ws + 3 * QSZ + (size_t)ns * PLANE_O16);
    float* attnbuf = (float*)(ws);                              // overlaps dead Qw/Kw

    qkv_proj_kernel<<<dim3(256, 2, 3), 256, 0, stream>>>(x, Wq, bq, Wk, bk, Wv, bv, Qw, Kw, Vw);
    vtrans_kernel<<<dim3(S_LEN / 64, CBATCH * NHEAD), 256, 0, stream>>>(Vw, Vt2);
    if (ns == 8) {
        attn_kernel<8><<<dim3(S_LEN / 32, CBATCH, 8), 256, 0, stream>>>(Qw, Kw, Vt2, ew, partO, den);
        combine_kernel<8><<<dim3((CBATCH * S_LEN * HID / 4) / 256), 256, 0, stream>>>(partO, den, attnbuf);
    } else if (ns == 4) {
        attn_kernel<4><<<dim3(S_LEN / 32, CBATCH, 4), 256, 0, stream>>>(Qw, Kw, Vt2, ew, partO, den);
        combine_kernel<4><<<dim3((CBATCH * S_LEN * HID / 4) / 256), 256, 0, stream>>>(partO, den, attnbuf);
    } else {
        attn_kernel<2><<<dim3(S_LEN / 32, CBATCH, 2), 256, 0, stream>>>(Qw, Kw, Vt2, ew, partO, den);
        combine_kernel<2><<<dim3((CBATCH * S_LEN * HID / 4) / 256), 256, 0, stream>>>(partO, den, attnbuf);
    }
    out_proj_kernel<<<dim3(256, 2), 256, 0, stream>>>(attnbuf, Wo, bo, out);
}

// Round 23
// 164.365 us; speedup vs baseline: 1.0864x; 1.0864x over previous
//
#include <hip/hip_runtime.h>
#include <hip/hip_bf16.h>
#include <cstdint>

#define S_LEN 4096
#define NHEAD 4
#define HDIM 32
#define HID 128
#define CBATCH 4
#define EPSW 1e-8f
#define NCHUNKS (S_LEN / 32)

typedef __attribute__((ext_vector_type(8))) short short8v;
typedef __attribute__((ext_vector_type(4))) float float4v;

__device__ __forceinline__ unsigned short f2bf(float f) {
    unsigned int u = __float_as_uint(f);
    return (unsigned short)((u + 0x7fffu + ((u >> 16) & 1u)) >> 16);
}

__device__ __forceinline__ float exp2_asm(float x) {
    float r;
    asm("v_exp_f32 %0, %1" : "=v"(r) : "v"(x));
    return r;
}

__device__ __forceinline__ unsigned cvt_pk_bf16(float lo, float hi) {
    unsigned r;
    asm("v_cvt_pk_bf16_f32 %0, %1, %2" : "=v"(r) : "v"(lo), "v"(hi));
    return r;
}

// async global->LDS, 16B per lane; LDS dest = wave-uniform base + lane*16
__device__ __forceinline__ void gload16(const void* g, void* l) {
    __builtin_amdgcn_global_load_lds(
        (const __attribute__((address_space(1))) void*)g,
        (__attribute__((address_space(3))) void*)l,
        16, 0, 0);
}

// ---------------------------------------------------------------------------
// Kernel 1: fused QKV projection.  out = (x @ W.T + b) [* SCALE*log2e for Q]
// ---------------------------------------------------------------------------
__global__ __launch_bounds__(256) void qkv_proj_kernel(
    const float* __restrict__ x,
    const float* __restrict__ Wq, const float* __restrict__ bq,
    const float* __restrict__ Wk, const float* __restrict__ bk,
    const float* __restrict__ Wv, const float* __restrict__ bv,
    unsigned short* __restrict__ Qo, unsigned short* __restrict__ Ko,
    unsigned short* __restrict__ Vo)
{
    __shared__ float xs[64][132];
    __shared__ float wsT[64][68];

    const int tid = threadIdx.x;
    const int mrow0 = blockIdx.x * 64;
    const int n0 = blockIdx.y * 64;
    const int p = blockIdx.z;
    const float* W    = (p == 0) ? Wq : (p == 1) ? Wk : Wv;
    const float* bias = (p == 0) ? bq : (p == 1) ? bk : bv;
    unsigned short* Out = (p == 0) ? Qo : (p == 1) ? Ko : Vo;

    for (int i = tid; i < 64 * 32; i += 256) {
        int r = i >> 5, c4 = (i & 31) * 4;
        *(float4*)&xs[r][c4] = *(const float4*)&x[(size_t)(mrow0 + r) * HID + c4];
    }

    float acc[4][4] = {};
    const int tr = tid >> 4;
    const int tc = tid & 15;

    for (int ph = 0; ph < 2; ++ph) {
        __syncthreads();
        for (int i = tid; i < 64 * 16; i += 256) {
            int r = i >> 4, c4 = (i & 15) * 4;
            float4 wv = *(const float4*)&W[(size_t)(n0 + r) * HID + ph * 64 + c4];
            wsT[c4 + 0][r] = wv.x;
            wsT[c4 + 1][r] = wv.y;
            wsT[c4 + 2][r] = wv.z;
            wsT[c4 + 3][r] = wv.w;
        }
        __syncthreads();
        #pragma unroll 4
        for (int k4 = 0; k4 < 16; ++k4) {
            float4 xv[4];
            #pragma unroll
            for (int i = 0; i < 4; ++i)
                xv[i] = *(const float4*)&xs[tr * 4 + i][ph * 64 + k4 * 4];
            #pragma unroll
            for (int kk = 0; kk < 4; ++kk) {
                float4 wv = *(const float4*)&wsT[k4 * 4 + kk][tc * 4];
                #pragma unroll
                for (int i = 0; i < 4; ++i) {
                    float xk = ((const float*)&xv[i])[kk];
                    acc[i][0] += xk * wv.x;
                    acc[i][1] += xk * wv.y;
                    acc[i][2] += xk * wv.z;
                    acc[i][3] += xk * wv.w;
                }
            }
        }
    }

    // SCALE * log2(e): exp(s*SCALE) == exp2(s * SCALE * log2e)
    const float scale = (p == 0) ? 0.25500544458521289f : 1.0f;
    float4 bv4 = *(const float4*)&bias[n0 + tc * 4];
    const int nbase = n0 + tc * 4;
    const int h = nbase >> 5;
    const int d = nbase & 31;
    #pragma unroll
    for (int i = 0; i < 4; ++i) {
        int m = mrow0 + tr * 4 + i;
        int c = m >> 12, s = m & 4095;
        unsigned short pk[4];
        pk[0] = f2bf((acc[i][0] + bv4.x) * scale);
        pk[1] = f2bf((acc[i][1] + bv4.y) * scale);
        pk[2] = f2bf((acc[i][2] + bv4.z) * scale);
        pk[3] = f2bf((acc[i][3] + bv4.w) * scale);
        *(uint2*)&Out[((size_t)(c * NHEAD + h) * S_LEN + s) * HDIM + d] = *(uint2*)pk;
    }
}

// ---------------------------------------------------------------------------
// Kernel 2: repack V (C,NH,S,HD) -> Vt2: exact PV A-fragment order.
// ---------------------------------------------------------------------------
__global__ __launch_bounds__(256) void vtrans_kernel(
    const unsigned short* __restrict__ V, unsigned short* __restrict__ Vt2)
{
    __shared__ unsigned short vs[64][40];
    const int tid = threadIdx.x;
    const int chh = blockIdx.y;
    const int s0 = blockIdx.x * 64;
    const size_t base = (size_t)chh * S_LEN * HDIM;
    {
        int r = tid >> 2, ch = (tid & 3) * 8;
        *(uint4*)&vs[r][ch] = *(const uint4*)&V[base + (size_t)(s0 + r) * HDIM + ch];
    }
    __syncthreads();
    {
        const int lchunk = tid >> 7;         // 0..1
        const int db = (tid >> 6) & 1;       // 0..1
        const int l = tid & 63;
        const int li = l & 15;
        const int g = l >> 4;
        unsigned short pk[8];
        #pragma unroll
        for (int j = 0; j < 8; ++j) {
            int key = lchunk * 32 + ((j < 4) ? (4 * g + j) : (16 + 4 * g + (j - 4)));
            pk[j] = vs[key][db * 16 + li];
        }
        size_t chunk = (size_t)(s0 >> 5) + lchunk;
        *(uint4*)&Vt2[(((size_t)chh * 2 + db) * NCHUNKS + chunk) * 512 + l * 8] = *(uint4*)pk;
    }
}

// ---------------------------------------------------------------------------
// Kernel 3: attention, split-K, dual key-tranche A/B (64 keys/iter) —
// r21/r22-validated body VERBATIM.  NS=4 (r21's best total).
// ew triple-buffered LDS (buf = it%3); kv fresh per iter into regs.
// vmcnt (FIFO per iter: kv x8 then ew x2): steady 10, last iter 8.
// Denominator via ones-MFMA; s_setprio around compute cluster.
// NOTE: plain __launch_bounds__(256) — (256,4) was the r3/5/6/7 poison.
// ---------------------------------------------------------------------------
template<int NS>
__global__ __launch_bounds__(256) void attn_kernel(
    const unsigned short* __restrict__ Q, const unsigned short* __restrict__ K,
    const unsigned short* __restrict__ Vt2, const float* __restrict__ ew,
    unsigned short* __restrict__ partO, float* __restrict__ den)
{
    const int KCHUNK = S_LEN / NS;
    const int NIT = KCHUNK / 64;

    __shared__ float ew_lds[3][2048];            // 3 x 8KB: [A 4 regions | B 4 regions]

    const int tid = threadIdx.x;
    const int w = tid >> 6;          // head
    const int lane = tid & 63;
    const int li = lane & 15;
    const int g = lane >> 4;
    const int c = blockIdx.y;
    const int qbase = blockIdx.x * 32;
    const int split = blockIdx.z;
    const int kb0 = split * KCHUNK;
    const int chh = c * NHEAD + w;

    const size_t hb = (size_t)chh * S_LEN * HDIM;
    const unsigned short* Qh = Q + hb;
    const unsigned short* Kh = K + hb;
    const float* ewc = ew + (size_t)c * S_LEN * S_LEN;

    short8v qf0 = *(const short8v*)&Qh[(size_t)(qbase + li) * HDIM + g * 8];
    short8v qf1 = *(const short8v*)&Qh[(size_t)(qbase + 16 + li) * HDIM + g * 8];

    short8v ones;
    #pragma unroll
    for (int j = 0; j < 8; ++j) ones[j] = (short)0x3F80;  // bf16 1.0

    // ew region w: rows qbase + (w>>1)*16 + li, cols kb + (w&1)*16 + g*4
    const float* ewA_src = ewc + (size_t)(qbase + (w >> 1) * 16 + li) * S_LEN + kb0
                         + (w & 1) * 16 + g * 4;
    const float* ewB_src = ewA_src + 32;
    const unsigned short* kp  = Kh + (size_t)(kb0 + li) * HDIM + g * 8;
    const unsigned short* vp0 = Vt2 + (((size_t)chh * 2 + 0) * NCHUNKS + (kb0 >> 5)) * 512 + lane * 8;
    const unsigned short* vp1 = Vt2 + (((size_t)chh * 2 + 1) * NCHUNKS + (kb0 >> 5)) * 512 + lane * 8;

    float4v o00 = {}, o01 = {}, o10 = {}, o11 = {};
    float4v dacc0 = {}, dacc1 = {};
    const float4v zero4 = {0.f, 0.f, 0.f, 0.f};

    #define CFENCE() asm volatile("" ::: "memory")

    // prologue: stage ew(0) A,B into buf 0
    gload16(ewA_src, &ew_lds[0][w * 256]);
    gload16(ewB_src, &ew_lds[0][1024 + w * 256]);
    ewA_src += 64; ewB_src += 64;
    CFENCE();

    int bew = 0;   // compute buffer = it % 3
    int sew = 1;   // stage buffer   = (it+1) % 3
    for (int it = 0; it < NIT; ++it) {
        // kv(it) A+B into regs (L2-resident; compiler auto-waits before use)
        short8v kfA0 = *(const short8v*)kp;
        short8v kfA1 = *(const short8v*)(kp + 512);
        short8v vfA0 = *(const short8v*)vp0;
        short8v vfA1 = *(const short8v*)vp1;
        short8v kfB0 = *(const short8v*)(kp + 1024);
        short8v kfB1 = *(const short8v*)(kp + 1536);
        short8v vfB0 = *(const short8v*)(vp0 + 512);
        short8v vfB1 = *(const short8v*)(vp1 + 512);
        CFENCE();
        if (it + 1 < NIT) {
            gload16(ewA_src, &ew_lds[sew][w * 256]);
            gload16(ewB_src, &ew_lds[sew][1024 + w * 256]);
            ewA_src += 64; ewB_src += 64;
        }
        // wait for own ew(it): younger = kv x8 [+ ew(it+1) x2 if staged]
        if (it + 1 < NIT) asm volatile("s_waitcnt vmcnt(10)" ::: "memory");
        else              asm volatile("s_waitcnt vmcnt(8)" ::: "memory");
        __builtin_amdgcn_s_barrier();
        CFENCE();

        const float* eb = ew_lds[bew];

        __builtin_amdgcn_s_setprio(1);
        // ---- tranche A ----
        {
            float4 e00 = *(const float4*)&eb[lane * 4];
            float4 e01 = *(const float4*)&eb[256 + lane * 4];
            float4 e10 = *(const float4*)&eb[512 + lane * 4];
            float4 e11 = *(const float4*)&eb[768 + lane * 4];

            float4v s0 = __builtin_amdgcn_mfma_f32_16x16x32_bf16(kfA0, qf0, zero4, 0, 0, 0);
            float4v s1 = __builtin_amdgcn_mfma_f32_16x16x32_bf16(kfA1, qf0, zero4, 0, 0, 0);
            float4v s2 = __builtin_amdgcn_mfma_f32_16x16x32_bf16(kfA0, qf1, zero4, 0, 0, 0);
            float4v s3 = __builtin_amdgcn_mfma_f32_16x16x32_bf16(kfA1, qf1, zero4, 0, 0, 0);

            float p0 = fmaxf(e00.x, EPSW) * exp2_asm(s0[0]);
            float p1 = fmaxf(e00.y, EPSW) * exp2_asm(s0[1]);
            float p2 = fmaxf(e00.z, EPSW) * exp2_asm(s0[2]);
            float p3 = fmaxf(e00.w, EPSW) * exp2_asm(s0[3]);
            float p4 = fmaxf(e01.x, EPSW) * exp2_asm(s1[0]);
            float p5 = fmaxf(e01.y, EPSW) * exp2_asm(s1[1]);
            float p6 = fmaxf(e01.z, EPSW) * exp2_asm(s1[2]);
            float p7 = fmaxf(e01.w, EPSW) * exp2_asm(s1[3]);
            union { short8v v; unsigned u[4]; } pu0;
            pu0.u[0] = cvt_pk_bf16(p0, p1);
            pu0.u[1] = cvt_pk_bf16(p2, p3);
            pu0.u[2] = cvt_pk_bf16(p4, p5);
            pu0.u[3] = cvt_pk_bf16(p6, p7);
            o00 = __builtin_amdgcn_mfma_f32_16x16x32_bf16(vfA0, pu0.v, o00, 0, 0, 0);
            o01 = __builtin_amdgcn_mfma_f32_16x16x32_bf16(vfA1, pu0.v, o01, 0, 0, 0);
            dacc0 = __builtin_amdgcn_mfma_f32_16x16x32_bf16(ones, pu0.v, dacc0, 0, 0, 0);

            float r0 = fmaxf(e10.x, EPSW) * exp2_asm(s2[0]);
            float r1 = fmaxf(e10.y, EPSW) * exp2_asm(s2[1]);
            float r2 = fmaxf(e10.z, EPSW) * exp2_asm(s2[2]);
            float r3 = fmaxf(e10.w, EPSW) * exp2_asm(s2[3]);
            float r4 = fmaxf(e11.x, EPSW) * exp2_asm(s3[0]);
            float r5 = fmaxf(e11.y, EPSW) * exp2_asm(s3[1]);
            float r6 = fmaxf(e11.z, EPSW) * exp2_asm(s3[2]);
            float r7 = fmaxf(e11.w, EPSW) * exp2_asm(s3[3]);
            union { short8v v; unsigned u[4]; } pu1;
            pu1.u[0] = cvt_pk_bf16(r0, r1);
            pu1.u[1] = cvt_pk_bf16(r2, r3);
            pu1.u[2] = cvt_pk_bf16(r4, r5);
            pu1.u[3] = cvt_pk_bf16(r6, r7);
            o10 = __builtin_amdgcn_mfma_f32_16x16x32_bf16(vfA0, pu1.v, o10, 0, 0, 0);
            o11 = __builtin_amdgcn_mfma_f32_16x16x32_bf16(vfA1, pu1.v, o11, 0, 0, 0);
            dacc1 = __builtin_amdgcn_mfma_f32_16x16x32_bf16(ones, pu1.v, dacc1, 0, 0, 0);
        }

        // ---- tranche B (independent of A until oacc joins) ----
        {
            float4 e00 = *(const float4*)&eb[1024 + lane * 4];
            float4 e01 = *(const float4*)&eb[1280 + lane * 4];
            float4 e10 = *(const float4*)&eb[1536 + lane * 4];
            float4 e11 = *(const float4*)&eb[1792 + lane * 4];

            float4v s0 = __builtin_amdgcn_mfma_f32_16x16x32_bf16(kfB0, qf0, zero4, 0, 0, 0);
            float4v s1 = __builtin_amdgcn_mfma_f32_16x16x32_bf16(kfB1, qf0, zero4, 0, 0, 0);
            float4v s2 = __builtin_amdgcn_mfma_f32_16x16x32_bf16(kfB0, qf1, zero4, 0, 0, 0);
            float4v s3 = __builtin_amdgcn_mfma_f32_16x16x32_bf16(kfB1, qf1, zero4, 0, 0, 0);

            float p0 = fmaxf(e00.x, EPSW) * exp2_asm(s0[0]);
            float p1 = fmaxf(e00.y, EPSW) * exp2_asm(s0[1]);
            float p2 = fmaxf(e00.z, EPSW) * exp2_asm(s0[2]);
            float p3 = fmaxf(e00.w, EPSW) * exp2_asm(s0[3]);
            float p4 = fmaxf(e01.x, EPSW) * exp2_asm(s1[0]);
            float p5 = fmaxf(e01.y, EPSW) * exp2_asm(s1[1]);
            float p6 = fmaxf(e01.z, EPSW) * exp2_asm(s1[2]);
            float p7 = fmaxf(e01.w, EPSW) * exp2_asm(s1[3]);
            union { short8v v; unsigned u[4]; } pu0;
            pu0.u[0] = cvt_pk_bf16(p0, p1);
            pu0.u[1] = cvt_pk_bf16(p2, p3);
            pu0.u[2] = cvt_pk_bf16(p4, p5);
            pu0.u[3] = cvt_pk_bf16(p6, p7);
            o00 = __builtin_amdgcn_mfma_f32_16x16x32_bf16(vfB0, pu0.v, o00, 0, 0, 0);
            o01 = __builtin_amdgcn_mfma_f32_16x16x32_bf16(vfB1, pu0.v, o01, 0, 0, 0);
            dacc0 = __builtin_amdgcn_mfma_f32_16x16x32_bf16(ones, pu0.v, dacc0, 0, 0, 0);

            float r0 = fmaxf(e10.x, EPSW) * exp2_asm(s2[0]);
            float r1 = fmaxf(e10.y, EPSW) * exp2_asm(s2[1]);
            float r2 = fmaxf(e10.z, EPSW) * exp2_asm(s2[2]);
            float r3 = fmaxf(e10.w, EPSW) * exp2_asm(s2[3]);
            float r4 = fmaxf(e11.x, EPSW) * exp2_asm(s3[0]);
            float r5 = fmaxf(e11.y, EPSW) * exp2_asm(s3[1]);
            float r6 = fmaxf(e11.z, EPSW) * exp2_asm(s3[2]);
            float r7 = fmaxf(e11.w, EPSW) * exp2_asm(s3[3]);
            union { short8v v; unsigned u[4]; } pu1;
            pu1.u[0] = cvt_pk_bf16(r0, r1);
            pu1.u[1] = cvt_pk_bf16(r2, r3);
            pu1.u[2] = cvt_pk_bf16(r4, r5);
            pu1.u[3] = cvt_pk_bf16(r6, r7);
            o10 = __builtin_amdgcn_mfma_f32_16x16x32_bf16(vfB0, pu1.v, o10, 0, 0, 0);
            o11 = __builtin_amdgcn_mfma_f32_16x16x32_bf16(vfB1, pu1.v, o11, 0, 0, 0);
            dacc1 = __builtin_amdgcn_mfma_f32_16x16x32_bf16(ones, pu1.v, dacc1, 0, 0, 0);
        }
        __builtin_amdgcn_s_setprio(0);

        kp += 2048;          // 64 keys * 32 dims
        vp0 += 1024;         // 2 chunks
        vp1 += 1024;
        bew = (bew == 2) ? 0 : bew + 1;
        sew = (sew == 2) ? 0 : sew + 1;
    }
    #undef CFENCE

    // every C-row of dacc holds the full key-sum for q-col (lane&15)
    const float den0 = dacc0[0];
    const float den1 = dacc1[0];

    const size_t pbase = (((size_t)split * CBATCH + c) * NHEAD + w) * S_LEN + qbase;
    {
        const size_t pb = pbase + li;
        uint2 s;
        s.x = cvt_pk_bf16(o00[0], o00[1]);
        s.y = cvt_pk_bf16(o00[2], o00[3]);
        *(uint2*)&partO[pb * HDIM + 0 * 16 + g * 4] = s;
        s.x = cvt_pk_bf16(o01[0], o01[1]);
        s.y = cvt_pk_bf16(o01[2], o01[3]);
        *(uint2*)&partO[pb * HDIM + 1 * 16 + g * 4] = s;
        if (g == 0) den[pb] = den0;
    }
    {
        const size_t pb = pbase + 16 + li;
        uint2 s;
        s.x = cvt_pk_bf16(o10[0], o10[1]);
        s.y = cvt_pk_bf16(o10[2], o10[3]);
        *(uint2*)&partO[pb * HDIM + 0 * 16 + g * 4] = s;
        s.x = cvt_pk_bf16(o11[0], o11[1]);
        s.y = cvt_pk_bf16(o11[2], o11[3]);
        *(uint2*)&partO[pb * HDIM + 1 * 16 + g * 4] = s;
        if (g == 0) den[pb] = den1;
    }
}

// ---------------------------------------------------------------------------
// Kernel 4: output projection with FUSED split-combine.
// Stages x-tile directly from bf16 partO + den (normalizing inline) —
// eliminates the combine kernel and the attnbuf round-trip (16 MB).
// Unpack arithmetic identical to the r16-validated combine kernel.
// ---------------------------------------------------------------------------
template<int NS>
__global__ __launch_bounds__(256) void out_proj_fused_kernel(
    const unsigned short* __restrict__ pO, const float* __restrict__ den,
    const float* __restrict__ Wo, const float* __restrict__ bo,
    float* __restrict__ out)
{
    __shared__ float xs[64][132];
    __shared__ float wsT[64][68];

    const int tid = threadIdx.x;
    const int mrow0 = blockIdx.x * 64;
    const int n0 = blockIdx.y * 64;
    const size_t plane = (size_t)CBATCH * NHEAD * S_LEN;

    // staging with inline combine: xs[r][col] = (sum_s partO) / (sum_s den)
    for (int i = tid; i < 64 * 32; i += 256) {
        int r = i >> 5, c4 = (i & 31) * 4;      // c4 in {0,4,...,124}
        int m = mrow0 + r;
        int c = m >> 12, q = m & 4095;
        int h = c4 >> 5, d4 = c4 & 31;
        const size_t bq = ((size_t)c * NHEAD + h) * S_LEN + q;
        float a0 = 0.f, a1 = 0.f, a2 = 0.f, a3 = 0.f, dsum = 0.f;
        #pragma unroll
        for (int s = 0; s < NS; ++s) {
            const size_t b = (size_t)s * plane + bq;
            uint2 a = *(const uint2*)&pO[b * HDIM + d4];
            a0 += __uint_as_float(a.x << 16);
            a1 += __uint_as_float(a.x & 0xffff0000u);
            a2 += __uint_as_float(a.y << 16);
            a3 += __uint_as_float(a.y & 0xffff0000u);
            dsum += den[b];
        }
        float inv = 1.0f / dsum;
        xs[r][c4 + 0] = a0 * inv;
        xs[r][c4 + 1] = a1 * inv;
        xs[r][c4 + 2] = a2 * inv;
        xs[r][c4 + 3] = a3 * inv;
    }

    float acc[4][4] = {};
    const int tr = tid >> 4;
    const int tc = tid & 15;

    for (int ph = 0; ph < 2; ++ph) {
        __syncthreads();
        for (int i = tid; i < 64 * 16; i += 256) {
            int r = i >> 4, c4 = (i & 15) * 4;
            float4 wv = *(const float4*)&Wo[(size_t)(n0 + r) * HID + ph * 64 + c4];
            wsT[c4 + 0][r] = wv.x;
            wsT[c4 + 1][r] = wv.y;
            wsT[c4 + 2][r] = wv.z;
            wsT[c4 + 3][r] = wv.w;
        }
        __syncthreads();
        #pragma unroll 4
        for (int k4 = 0; k4 < 16; ++k4) {
            float4 xv[4];
            #pragma unroll
            for (int i = 0; i < 4; ++i)
                xv[i] = *(const float4*)&xs[tr * 4 + i][ph * 64 + k4 * 4];
            #pragma unroll
            for (int kk = 0; kk < 4; ++kk) {
                float4 wv = *(const float4*)&wsT[k4 * 4 + kk][tc * 4];
                #pragma unroll
                for (int i = 0; i < 4; ++i) {
                    float xk = ((const float*)&xv[i])[kk];
                    acc[i][0] += xk * wv.x;
                    acc[i][1] += xk * wv.y;
                    acc[i][2] += xk * wv.z;
                    acc[i][3] += xk * wv.w;
                }
            }
        }
    }

    float4 bv4 = *(const float4*)&bo[n0 + tc * 4];
    #pragma unroll
    for (int i = 0; i < 4; ++i) {
        int m = mrow0 + tr * 4 + i;
        float4 o;
        o.x = acc[i][0] + bv4.x;
        o.y = acc[i][1] + bv4.y;
        o.z = acc[i][2] + bv4.z;
        o.w = acc[i][3] + bv4.w;
        *(float4*)&out[(size_t)m * HID + n0 + tc * 4] = o;
    }
}

extern "C" void kernel_launch(void* const* d_in, const int* in_sizes, int n_in,
                              void* d_out, int out_size, void* d_ws, size_t ws_size,
                              hipStream_t stream) {
    const float* x  = (const float*)d_in[0];
    const float* ew = (const float*)d_in[1];
    const float* Wq = (const float*)d_in[2];
    const float* bq = (const float*)d_in[3];
    const float* Wk = (const float*)d_in[4];
    const float* bk = (const float*)d_in[5];
    const float* Wv = (const float*)d_in[6];
    const float* bv = (const float*)d_in[7];
    const float* Wo = (const float*)d_in[8];
    const float* bo = (const float*)d_in[9];
    float* out = (float*)d_out;

    char* ws = (char*)d_ws;
    const size_t QSZ = (size_t)CBATCH * NHEAD * S_LEN * HDIM * sizeof(unsigned short);  // 4 MiB
    const size_t PLANE_O16 = (size_t)CBATCH * NHEAD * S_LEN * HDIM * sizeof(unsigned short); // 4 MiB
    const size_t PLANE_D = (size_t)CBATCH * NHEAD * S_LEN * sizeof(float);              // 256 KiB

    const size_t need4 = 3 * QSZ + 4 * PLANE_O16 + 4 * PLANE_D;
    const int ns = (ws_size >= need4) ? 4 : 2;

    unsigned short* Qw  = (unsigned short*)(ws);
    unsigned short* Kw  = (unsigned short*)(ws + QSZ);
    unsigned short* Vt2 = (unsigned short*)(ws + 2 * QSZ);
    unsigned short* Vw  = (unsigned short*)(ws + 3 * QSZ);
    unsigned short* partO = (unsigned short*)(ws + 3 * QSZ);   // overlaps dead Vw
    float* den   = (float*)(ws + 3 * QSZ + (size_t)ns * PLANE_O16);

    qkv_proj_kernel<<<dim3(256, 2, 3), 256, 0, stream>>>(x, Wq, bq, Wk, bk, Wv, bv, Qw, Kw, Vw);
    vtrans_kernel<<<dim3(S_LEN / 64, CBATCH * NHEAD), 256, 0, stream>>>(Vw, Vt2);
    if (ns == 4) {
        attn_kernel<4><<<dim3(S_LEN / 32, CBATCH, 4), 256, 0, stream>>>(Qw, Kw, Vt2, ew, partO, den);
        out_proj_fused_kernel<4><<<dim3(256, 2), 256, 0, stream>>>(partO, den, Wo, bo, out);
    } else {
        attn_kernel<2><<<dim3(S_LEN / 32, CBATCH, 2), 256, 0, stream>>>(Qw, Kw, Vt2, ew, partO, den);
        out_proj_fused_kernel<2><<<dim3(256, 2), 256, 0, stream>>>(partO, den, Wo, bo, out);
    }
}